// Round 12
// baseline (201.132 us; speedup 1.0000x reference)
//
#include <hip/hip_runtime.h>
#include <cstdint>
#include <cstddef>

#define TOKENS 4096
#define DM 512
#define DF 2048
#define NE 8
#define NPAIR 8192  // TOKENS * TOPK
#define SPLIT 2     // split-K factor for GEMM2 (f32 partials)

typedef unsigned short u16;
typedef __attribute__((ext_vector_type(8))) short short8;
typedef __attribute__((ext_vector_type(4))) float f32x4;

// fp32 -> bf16 round-to-nearest-even (finite inputs only)
__device__ __forceinline__ u16 f2b(float x) {
  uint32_t u = __builtin_bit_cast(uint32_t, x);
  uint32_t r = (u + 0x7fffu + ((u >> 16) & 1u)) >> 16;
  return (u16)r;
}

__device__ __forceinline__ void gl_lds16(const void* gsrc, void* ldst) {
  __builtin_amdgcn_global_load_lds(
      (__attribute__((address_space(1))) void*)(gsrc),
      (__attribute__((address_space(3))) void*)(ldst), 16, 0, 0);
}

// bijective XCD swizzle (requires nwg % 8 == 0): blocks sharing an M-tile
// get consecutive wg on one XCD -> shared A-chunk/B-panels become L2-local.
__device__ __forceinline__ int xcd_swz(int flat, int nwg) {
  return (flat & 7) * (nwg >> 3) + (flat >> 3);
}

// ---------------- prep: routing (atomic-free, R9-verbatim) | hidden cvt | tr wi ----
__global__ __launch_bounds__(256) void prep_kernel(
    const int* __restrict__ eidx, const float* __restrict__ hidden, u16* __restrict__ hidden_b,
    const float* __restrict__ wi, u16* __restrict__ wi_t,
    int* __restrict__ pair_token, int* __restrict__ pair_pos,
    int* __restrict__ seg_off, int* __restrict__ seg_cnt,
    int* __restrict__ tl_e, int* __restrict__ tl_mt) {
  __shared__ __align__(16) float t[64][65];
  int bid = blockIdx.x;
  int tid = threadIdx.x;
  if (bid == 0) {
    // ---- atomic-free routing: histogram + scan + scatter ----
    int* wsums = (int*)&t[0][0];   // 32 ints
    int* wbase = wsums + 32;       // 32 ints
    int* tot = wbase + 32;         // 8 ints
    int* off = tot + 8;            // 8 ints
    const int lane = tid & 63, wv = tid >> 6;
    int ei[32];
#pragma unroll
    for (int k = 0; k < 8; ++k) {
      int4 v = ((const int4*)eidx)[tid * 8 + k];
      ei[4 * k + 0] = v.x; ei[4 * k + 1] = v.y;
      ei[4 * k + 2] = v.z; ei[4 * k + 3] = v.w;
    }
    int c[8];
#pragma unroll
    for (int e = 0; e < NE; ++e) c[e] = 0;
#pragma unroll
    for (int j = 0; j < 32; ++j)
#pragma unroll
      for (int e = 0; e < NE; ++e) c[e] += (ei[j] == e) ? 1 : 0;
    int pre[8], wtot[8];
#pragma unroll
    for (int e = 0; e < NE; ++e) {
      int v = c[e];
      int s = v;
#pragma unroll
      for (int d = 1; d < 64; d <<= 1) {
        int u = __shfl_up(s, d, 64);
        if (lane >= d) s += u;
      }
      pre[e] = s - v;
      wtot[e] = __shfl(s, 63, 64);
    }
    if (lane == 0) {
#pragma unroll
      for (int e = 0; e < NE; ++e) wsums[e * 4 + wv] = wtot[e];
    }
    __syncthreads();
    if (tid < 32) {
      int e = tid >> 2, w = tid & 3;
      int b = 0;
      for (int j = 0; j < 4; ++j) {
        int v = wsums[e * 4 + j];
        if (j < w) b += v;
      }
      wbase[e * 4 + w] = b;
      if (w == 3) tot[e] = b + wsums[e * 4 + 3];
    }
    __syncthreads();
    if (tid == 0) {
      int a = 0;
      for (int e = 0; e < NE; ++e) { off[e] = a; a += tot[e]; }
      int n = 0;
      for (int e = 0; e < NE; ++e) {
        int ntl = (tot[e] + 127) >> 7;
        for (int m = 0; m < ntl && n < 128; ++m, ++n) { tl_e[n] = e; tl_mt[n] = m; }
      }
      for (; n < 128; ++n) { tl_e[n] = -1; tl_mt[n] = 0; }
    }
    __syncthreads();
    if (tid < NE) { seg_off[tid] = off[tid]; seg_cnt[tid] = tot[tid]; }
    const int base = tid * 32;
#pragma unroll
    for (int e = 0; e < NE; ++e) {
      int p = off[e] + wbase[e * 4 + wv] + pre[e];
#pragma unroll
      for (int j = 0; j < 32; ++j) {
        if (ei[j] == e) {
          int i = base + j;
          pair_token[p] = i >> 1;
          pair_pos[i] = p;
          p++;
        }
      }
    }
  } else if (bid <= 2048) {
    int i = (bid - 1) * 256 + tid;  // float4 group
    float4 v = ((const float4*)hidden)[i];
    ushort4 o;
    o.x = f2b(v.x); o.y = f2b(v.y); o.z = f2b(v.z); o.w = f2b(v.w);
    ((ushort4*)hidden_b)[i] = o;
  } else {
    // wi transpose: [8][512][2048] f32 -> wi_t [8][2048][512] bf16
    const int R = DM, C = DF;
    int f = bid - 2049;
    int e = f >> 8;
    int cb = (f & 31) * 64, rb = ((f >> 5) & 7) * 64;
    const float* s = wi + (size_t)e * R * C;
    u16* d = wi_t + (size_t)e * R * C;
    int r = tid >> 4, cq = tid & 15;
#pragma unroll
    for (int i = 0; i < 4; ++i) {
      float4 v = *(const float4*)&s[(size_t)(rb + r + 16 * i) * C + cb + cq * 4];
      t[r + 16 * i][cq * 4 + 0] = v.x;
      t[r + 16 * i][cq * 4 + 1] = v.y;
      t[r + 16 * i][cq * 4 + 2] = v.z;
      t[r + 16 * i][cq * 4 + 3] = v.w;
    }
    __syncthreads();
    int rq = tid & 15, c0 = tid >> 4;
#pragma unroll
    for (int i = 0; i < 4; ++i) {
      int c = c0 + 16 * i;
      ushort4 o;
      o.x = f2b(t[rq * 4 + 0][c]);
      o.y = f2b(t[rq * 4 + 1][c]);
      o.z = f2b(t[rq * 4 + 2][c]);
      o.w = f2b(t[rq * 4 + 3][c]);
      *(ushort4*)&d[(size_t)(cb + c) * R + rb + rq * 4] = o;
    }
  }
}

// ---------------- GEMM1: R11 body + fused wo-transpose z-planes (R1-proven overlap) ----
__global__ __launch_bounds__(256) void gemm1_kernel(
    const u16* __restrict__ A,         // hidden_b [4096][512]
    const u16* __restrict__ Bt,        // wi_t [NE][2048][512]
    const int* __restrict__ pair_token,
    const int* __restrict__ seg_off, const int* __restrict__ seg_cnt,
    const int* __restrict__ tl_e, const int* __restrict__ tl_mt,
    u16* __restrict__ out_b,           // act
    const float* __restrict__ tr_src, u16* __restrict__ tr_dst) {
  __shared__ __align__(16) char smem[65536];  // 2 bufs x (A 16K + B 16K)
  if (blockIdx.z > 0) {
    // wo transpose: [8][2048][512] f32 -> wo_t [8][512][2048] bf16
    // Runs in gemm1's LDS/latency slack (GEMM blocks cap at 2/CU by LDS).
    int flat = (blockIdx.z - 1) * 1152 + blockIdx.y * 16 + blockIdx.x;
    if (flat < 2048) {
      const int R = DF, C = DM;
      float(*t)[65] = (float(*)[65])smem;
      int tid = threadIdx.x;
      int e = flat >> 8;
      int cb = (flat & 7) * 64, rb = ((flat >> 3) & 31) * 64;
      const float* s = tr_src + (size_t)e * R * C;
      u16* d = tr_dst + (size_t)e * R * C;
      int r = tid >> 4, cq = tid & 15;
#pragma unroll
      for (int i = 0; i < 4; ++i) {
        float4 v = *(const float4*)&s[(size_t)(rb + r + 16 * i) * C + cb + cq * 4];
        t[r + 16 * i][cq * 4 + 0] = v.x;
        t[r + 16 * i][cq * 4 + 1] = v.y;
        t[r + 16 * i][cq * 4 + 2] = v.z;
        t[r + 16 * i][cq * 4 + 3] = v.w;
      }
      __syncthreads();
      int rq = tid & 15, c0 = tid >> 4;
#pragma unroll
      for (int i = 0; i < 4; ++i) {
        int c = c0 + 16 * i;
        ushort4 o;
        o.x = f2b(t[rq * 4 + 0][c]);
        o.y = f2b(t[rq * 4 + 1][c]);
        o.z = f2b(t[rq * 4 + 2][c]);
        o.w = f2b(t[rq * 4 + 3][c]);
        *(ushort4*)&d[(size_t)(cb + c) * R + rb + rq * 4] = o;
      }
    }
    return;
  }
  const int wg = xcd_swz(blockIdx.y * 16 + blockIdx.x, 1152);
  const int nt = wg & 15;
  const int ytile = wg >> 4;
  const int e = tl_e[ytile];
  if (e < 0) return;
  const int mt = tl_mt[ytile];
  const int cnt = seg_cnt[e];
  const int off = seg_off[e];
  const int tid = threadIdx.x;
  const int wave = tid >> 6, lane = tid & 63;

  const int r0 = wave * 32;
  const int cidx = lane & 7;
  const int rsub = lane >> 3;
  const int csrc = (cidx ^ rsub) * 8;

  const u16* aSrc[4];
  const u16* bSrc[4];
  const u16* BtBase = Bt + ((size_t)e * DF + (size_t)nt * 128) * DM;
#pragma unroll
  for (int g = 0; g < 4; ++g) {
    int rl = r0 + 8 * g + rsub;
    int m = mt * 128 + rl;
    if (m > cnt - 1) m = cnt - 1;
    int srow = pair_token[off + m];
    aSrc[g] = A + (size_t)srow * DM + csrc;
    bSrc[g] = BtBase + (size_t)rl * DM + csrc;
  }

  const int wm = wave >> 1, wn = wave & 1;
  const int rl16 = lane & 15;
  const int q = lane >> 4;
  const int rx = rl16 & 7;

  f32x4 acc[4][4];
#pragma unroll
  for (int i = 0; i < 4; ++i)
#pragma unroll
    for (int j = 0; j < 4; ++j)
#pragma unroll
      for (int r = 0; r < 4; ++r) acc[i][j][r] = 0.0f;

#define G1_STAGE(buf, kofs)                                      \
  do {                                                           \
    u16* Ad_ = (u16*)smem + (buf)*16384;                         \
    u16* Bd_ = Ad_ + 8192;                                       \
    _Pragma("unroll") for (int g = 0; g < 4; ++g) {              \
      gl_lds16(aSrc[g] + (kofs), Ad_ + (r0 + 8 * g) * 64);       \
      gl_lds16(bSrc[g] + (kofs), Bd_ + (r0 + 8 * g) * 64);       \
    }                                                            \
  } while (0)

#define G1_COMPUTE(buf)                                                           \
  do {                                                                            \
    const u16* Al_ = (const u16*)smem + (buf)*16384;                              \
    const u16* Bl_ = Al_ + 8192;                                                  \
    _Pragma("unroll") for (int hb = 0; hb < 2; ++hb) {                            \
      const int jofs = ((q + 4 * hb) ^ rx) * 8;                                   \
      short8 af[4], bf[4];                                                        \
      _Pragma("unroll") for (int mi = 0; mi < 4; ++mi)                            \
        af[mi] = *(const short8*)&Al_[(wm * 64 + mi * 16 + rl16) * 64 + jofs];    \
      _Pragma("unroll") for (int ni = 0; ni < 4; ++ni)                            \
        bf[ni] = *(const short8*)&Bl_[(wn * 64 + ni * 16 + rl16) * 64 + jofs];    \
      _Pragma("unroll") for (int mi = 0; mi < 4; ++mi)                            \
        _Pragma("unroll") for (int ni = 0; ni < 4; ++ni)                          \
          acc[mi][ni] =                                                           \
              __builtin_amdgcn_mfma_f32_16x16x32_bf16(af[mi], bf[ni], acc[mi][ni], 0, 0, 0); \
    }                                                                             \
  } while (0)

  // 2-phase prefetch: STAGE(t+1) in flight during COMPUTE(t); 1 barrier/step.
  G1_STAGE(0, 0);
  __syncthreads();
  int cur = 0;
#pragma unroll
  for (int t = 0; t < (DM / 64) - 1; ++t) {
    G1_STAGE(cur ^ 1, (t + 1) * 64);
    G1_COMPUTE(cur);
    __syncthreads();
    cur ^= 1;
  }
  G1_COMPUTE(cur);
#undef G1_STAGE
#undef G1_COMPUTE

  const int rowq = (lane >> 4) * 4;
#pragma unroll
  for (int mi = 0; mi < 4; ++mi) {
#pragma unroll
    for (int r = 0; r < 4; ++r) {
      int m = mt * 128 + wm * 64 + mi * 16 + rowq + r;
      if (m < cnt) {
        size_t rowp = (size_t)(off + m) * DF;
#pragma unroll
        for (int ni = 0; ni < 4; ++ni) {
          int n = nt * 128 + wn * 64 + ni * 16 + rl16;
          float v = acc[mi][ni][r];
          v = v > 0.0f ? v : 0.0f;
          out_b[rowp + n] = f2b(v);
        }
      }
    }
  }
}

// ---------------- GEMM2: R11-verbatim (BK=64 2-phase + XCD swizzle), f32 partials ----
// Ypart[sp][p][n] = sum_{k in [sp*ks,+ks)} act[p][k] * wo_t[e][n][k]
__global__ __launch_bounds__(256) void gemm2_kernel(
    const u16* __restrict__ A,         // act [8192][2048]
    const u16* __restrict__ Bt,        // wo_t [NE][512][2048]
    const int* __restrict__ seg_off, const int* __restrict__ seg_cnt,
    const int* __restrict__ tl_e, const int* __restrict__ tl_mt,
    float* __restrict__ out_f,
    int nt_mask, int sp_shift, int ks) {
  const int nx = gridDim.x;
  const int wg = xcd_swz(blockIdx.y * nx + blockIdx.x, nx * 72);
  const int xb = wg % nx;
  const int ytile = wg / nx;
  const int e = tl_e[ytile];
  if (e < 0) return;
  const int mt = tl_mt[ytile];
  const int cnt = seg_cnt[e];
  const int off = seg_off[e];
  const int nt = xb & nt_mask;
  const int sp = xb >> sp_shift;
  const int kb = sp * ks;
  const int nsteps = ks >> 6;  // BK=64
  const int tid = threadIdx.x;
  const int wave = tid >> 6, lane = tid & 63;

  __shared__ __align__(16) char smem[65536];  // 2 bufs x (A 16K + B 16K)

  const int r0 = wave * 32;
  const int cidx = lane & 7;
  const int rsub = lane >> 3;
  const int csrc = (cidx ^ rsub) * 8;

  const u16* aSrc[4];
  const u16* bSrc[4];
  const u16* BtBase = Bt + ((size_t)e * DM + (size_t)nt * 128) * DF;
#pragma unroll
  for (int g = 0; g < 4; ++g) {
    int rl = r0 + 8 * g + rsub;
    int m = mt * 128 + rl;
    if (m > cnt - 1) m = cnt - 1;  // clamp padding rows to valid data
    aSrc[g] = A + (size_t)(off + m) * DF + csrc + kb;
    bSrc[g] = BtBase + (size_t)rl * DF + csrc + kb;
  }

  const int wm = wave >> 1, wn = wave & 1;
  const int rl16 = lane & 15;
  const int q = lane >> 4;
  const int rx = rl16 & 7;

  f32x4 acc[4][4];
#pragma unroll
  for (int i = 0; i < 4; ++i)
#pragma unroll
    for (int j = 0; j < 4; ++j)
#pragma unroll
      for (int r = 0; r < 4; ++r) acc[i][j][r] = 0.0f;

#define G2_STAGE(buf, kofs)                                      \
  do {                                                           \
    u16* Ad_ = (u16*)smem + (buf)*16384;                         \
    u16* Bd_ = Ad_ + 8192;                                       \
    _Pragma("unroll") for (int g = 0; g < 4; ++g) {              \
      gl_lds16(aSrc[g] + (kofs), Ad_ + (r0 + 8 * g) * 64);       \
      gl_lds16(bSrc[g] + (kofs), Bd_ + (r0 + 8 * g) * 64);       \
    }                                                            \
  } while (0)

#define G2_COMPUTE(buf)                                                           \
  do {                                                                            \
    const u16* Al_ = (const u16*)smem + (buf)*16384;                              \
    const u16* Bl_ = Al_ + 8192;                                                  \
    _Pragma("unroll") for (int hb = 0; hb < 2; ++hb) {                            \
      const int jofs = ((q + 4 * hb) ^ rx) * 8;                                   \
      short8 af[4], bf[4];                                                        \
      _Pragma("unroll") for (int mi = 0; mi < 4; ++mi)                            \
        af[mi] = *(const short8*)&Al_[(wm * 64 + mi * 16 + rl16) * 64 + jofs];    \
      _Pragma("unroll") for (int ni = 0; ni < 4; ++ni)                            \
        bf[ni] = *(const short8*)&Bl_[(wn * 64 + ni * 16 + rl16) * 64 + jofs];    \
      _Pragma("unroll") for (int mi = 0; mi < 4; ++mi)                            \
        _Pragma("unroll") for (int ni = 0; ni < 4; ++ni)                          \
          acc[mi][ni] =                                                           \
              __builtin_amdgcn_mfma_f32_16x16x32_bf16(af[mi], bf[ni], acc[mi][ni], 0, 0, 0); \
    }                                                                             \
  } while (0)

  // 2-phase prefetch: STAGE(t+1) in flight during COMPUTE(t); 1 barrier/step.
  G2_STAGE(0, 0);
  __syncthreads();
  int cur = 0;
  for (int t = 0; t < nsteps - 1; ++t) {
    G2_STAGE(cur ^ 1, (t + 1) << 6);
    G2_COMPUTE(cur);
    __syncthreads();
    cur ^= 1;
  }
  G2_COMPUTE(cur);
#undef G2_STAGE
#undef G2_COMPUTE

  float* outp = out_f + (size_t)sp * NPAIR * DM;
  const int rowq = (lane >> 4) * 4;
#pragma unroll
  for (int mi = 0; mi < 4; ++mi) {
#pragma unroll
    for (int r = 0; r < 4; ++r) {
      int m = mt * 128 + wm * 64 + mi * 16 + rowq + r;
      if (m < cnt) {
        size_t rowp = (size_t)(off + m) * DM;
#pragma unroll
        for (int ni = 0; ni < 4; ++ni) {
          int n = nt * 128 + wn * 64 + ni * 16 + rl16;
          outp[rowp + n] = acc[mi][ni][r];
        }
      }
    }
  }
}

// ---------------- combine (R9-verbatim, f32 partials) ----------------
__global__ void combine_kernel(const float* __restrict__ hidden,
                               const float* __restrict__ prob,
                               const int* __restrict__ pair_pos,
                               const float* __restrict__ Ypart,
                               float* __restrict__ out, int nsplit) {
  int i = blockIdx.x * 256 + threadIdx.x;  // group of 4 floats
  int t = i >> 7;                          // 128 groups per token (512/4)
  int g = i & 127;
  int p0 = pair_pos[2 * t], p1 = pair_pos[2 * t + 1];
  float c0 = 0.5f * prob[2 * t];
  float c1 = 0.25f * prob[2 * t + 1];
  float4 a = {0.f, 0.f, 0.f, 0.f}, b = {0.f, 0.f, 0.f, 0.f};
  for (int s = 0; s < nsplit; ++s) {
    const float4* Y = (const float4*)(Ypart + (size_t)s * NPAIR * DM);
    float4 va = Y[(size_t)p0 * 128 + g];
    float4 vb = Y[(size_t)p1 * 128 + g];
    a.x += va.x; a.y += va.y; a.z += va.z; a.w += va.w;
    b.x += vb.x; b.y += vb.y; b.z += vb.z; b.w += vb.w;
  }
  float4 h = ((const float4*)hidden)[i];
  float4 r, o;
  r.x = c0 * a.x + c1 * b.x;
  r.y = c0 * a.y + c1 * b.y;
  r.z = c0 * a.z + c1 * b.z;
  r.w = c0 * a.w + c1 * b.w;
  o.x = (r.x != 0.0f) ? r.x : h.x;
  o.y = (r.y != 0.0f) ? r.y : h.y;
  o.z = (r.z != 0.0f) ? r.z : h.z;
  o.w = (r.w != 0.0f) ? r.w : h.w;
  ((float4*)out)[i] = o;
}

extern "C" void kernel_launch(void* const* d_in, const int* in_sizes, int n_in,
                              void* d_out, int out_size, void* d_ws, size_t ws_size,
                              hipStream_t stream) {
  const float* hidden = (const float*)d_in[0];
  const float* prob = (const float*)d_in[1];
  const float* wi = (const float*)d_in[2];
  const float* wo = (const float*)d_in[3];
  const int* eidx = (const int*)d_in[4];
  float* out = (float*)d_out;

  char* ws = (char*)d_ws;
  u16* hidden_b = (u16*)(ws + 0);                     //  4 MB [4096][512] bf16
  u16* wi_t = (u16*)(ws + ((size_t)4 << 20));         // 16 MB [8][2048][512] bf16 (wi^T)
  u16* wo_t = (u16*)(ws + ((size_t)20 << 20));        // 16 MB [8][512][2048] bf16 (wo^T)
  u16* act = (u16*)(ws + ((size_t)36 << 20));         // 32 MB [8192][2048] bf16
  float* Ypart = (float*)(ws + ((size_t)68 << 20));   // 32 MB [2][8192][512] f32
  char* smalls = ws + ((size_t)132 << 20);
  int* pair_token = (int*)(smalls);
  int* pair_pos = (int*)(smalls + (64u << 10));
  int* seg_off = (int*)(smalls + (128u << 10));
  int* seg_cnt = (int*)(smalls + (128u << 10) + 256);
  int* tl_e = (int*)(smalls + (129u << 10));          // 128 ints
  int* tl_mt = (int*)(smalls + (129u << 10) + 512);   // 128 ints

  // 1) prep: routing+tilelist | hidden cvt | tr wi
  hipLaunchKernelGGL(prep_kernel, dim3(4097), dim3(256), 0, stream,
                     eidx, hidden, hidden_b, wi, wi_t,
                     pair_token, pair_pos, seg_off, seg_cnt, tl_e, tl_mt);
  // 2) GEMM1 (z=0, XCD-swizzled): act = relu(hidden @ wi[e]); + fused wo tr (z=1,2)
  hipLaunchKernelGGL(gemm1_kernel, dim3(16, 72, 3), dim3(256), 0, stream,
                     hidden_b, wi_t, pair_token, seg_off, seg_cnt, tl_e, tl_mt,
                     act, wo, wo_t);
  // 3) GEMM2: Ypart[sp] = act @ wo[e] (f32 partials); K=2048 split 2; BK=64 dbuf
  hipLaunchKernelGGL(gemm2_kernel, dim3(4 * SPLIT, 72, 1), dim3(256), 0, stream,
                     act, wo_t, seg_off, seg_cnt, tl_e, tl_mt,
                     Ypart, 3, 2, DF / SPLIT);
  // 4) combine + where(next!=0, next, hidden)
  hipLaunchKernelGGL(combine_kernel, dim3(2048), dim3(256), 0, stream,
                     hidden, prob, pair_pos, Ypart, out, SPLIT);
}

// Round 13
// 191.602 us; speedup vs baseline: 1.0497x; 1.0497x over previous
//
#include <hip/hip_runtime.h>
#include <cstdint>
#include <cstddef>

#define TOKENS 4096
#define DM 512
#define DF 2048
#define NE 8
#define NPAIR 8192  // TOKENS * TOPK
#define SPLIT 2     // split-K factor for GEMM2 (f32 partials)

typedef unsigned short u16;
typedef __attribute__((ext_vector_type(8))) short short8;
typedef __attribute__((ext_vector_type(4))) float f32x4;

// fp32 -> bf16 round-to-nearest-even (finite inputs only)
__device__ __forceinline__ u16 f2b(float x) {
  uint32_t u = __builtin_bit_cast(uint32_t, x);
  uint32_t r = (u + 0x7fffu + ((u >> 16) & 1u)) >> 16;
  return (u16)r;
}

__device__ __forceinline__ void gl_lds16(const void* gsrc, void* ldst) {
  __builtin_amdgcn_global_load_lds(
      (__attribute__((address_space(1))) void*)(gsrc),
      (__attribute__((address_space(3))) void*)(ldst), 16, 0, 0);
}

// bijective XCD swizzle (requires nwg % 8 == 0): blocks sharing an M-tile
// get consecutive wg on one XCD -> shared A-chunk/B-panels become L2-local.
__device__ __forceinline__ int xcd_swz(int flat, int nwg) {
  return (flat & 7) * (nwg >> 3) + (flat >> 3);
}

// ---------------- prep: routing (LDS-based, spill-proof) | hidden cvt | tr wi ----
__global__ __launch_bounds__(256) void prep_kernel(
    const int* __restrict__ eidx, const float* __restrict__ hidden, u16* __restrict__ hidden_b,
    const float* __restrict__ wi, u16* __restrict__ wi_t,
    int* __restrict__ pair_token, int* __restrict__ pair_pos,
    int* __restrict__ seg_off, int* __restrict__ seg_cnt,
    int* __restrict__ tl_e, int* __restrict__ tl_mt) {
  __shared__ __align__(16) float t[64][65];
  int bid = blockIdx.x;
  int tid = threadIdx.x;
  if (bid == 0) {
    // ---- atomic-free routing: histogram + scan + scatter.
    // Expert ids live PACKED IN LDS (4 per u32) — no big private array, no scratch spill.
    uint32_t* lds_ei = (uint32_t*)&t[0][0];   // 2048 u32 = 8 KB (8192 expert ids)
    int* wsums = (int*)(lds_ei + 2048);       // 32 ints
    int* wbase = wsums + 32;                  // 32 ints
    int* tot = wbase + 32;                    // 8 ints
    int* off = tot + 8;                       // 8 ints  (total 8.5 KB < 16.6 KB)
    const int lane = tid & 63, wv = tid >> 6;
    // phase 1: load my 32 pairs, histogram inline, pack ids into LDS
    int c[8];
#pragma unroll
    for (int e = 0; e < NE; ++e) c[e] = 0;
#pragma unroll
    for (int k = 0; k < 8; ++k) {
      int4 v = ((const int4*)eidx)[tid * 8 + k];
#pragma unroll
      for (int e = 0; e < NE; ++e) {
        c[e] += (v.x == e) ? 1 : 0;
        c[e] += (v.y == e) ? 1 : 0;
        c[e] += (v.z == e) ? 1 : 0;
        c[e] += (v.w == e) ? 1 : 0;
      }
      lds_ei[tid * 8 + k] = (uint32_t)(v.x & 0xff) | ((uint32_t)(v.y & 0xff) << 8) |
                            ((uint32_t)(v.z & 0xff) << 16) | ((uint32_t)(v.w & 0xff) << 24);
    }
    // phase 2a: per-expert exclusive scan across the wave (shfl)
    int pre[8], wtot[8];
#pragma unroll
    for (int e = 0; e < NE; ++e) {
      int v = c[e];
      int s = v;
#pragma unroll
      for (int d = 1; d < 64; d <<= 1) {
        int u = __shfl_up(s, d, 64);
        if (lane >= d) s += u;
      }
      pre[e] = s - v;
      wtot[e] = __shfl(s, 63, 64);
    }
    if (lane == 0) {
#pragma unroll
      for (int e = 0; e < NE; ++e) wsums[e * 4 + wv] = wtot[e];
    }
    __syncthreads();
    // phase 2b: cross-wave scan (4 waves) + expert totals
    if (tid < 32) {
      int e = tid >> 2, w = tid & 3;
      int b = 0;
      for (int j = 0; j < 4; ++j) {
        int v = wsums[e * 4 + j];
        if (j < w) b += v;
      }
      wbase[e * 4 + w] = b;
      if (w == 3) tot[e] = b + wsums[e * 4 + 3];
    }
    __syncthreads();
    // phase 2c: expert base offsets + tile list (thread 0)
    if (tid == 0) {
      int a = 0;
      for (int e = 0; e < NE; ++e) { off[e] = a; a += tot[e]; }
      int n = 0;
      for (int e = 0; e < NE; ++e) {
        int ntl = (tot[e] + 127) >> 7;
        for (int m = 0; m < ntl && n < 128; ++m, ++n) { tl_e[n] = e; tl_mt[n] = m; }
      }
      for (; n < 128; ++n) { tl_e[n] = -1; tl_mt[n] = 0; }
    }
    __syncthreads();
    if (tid < NE) { seg_off[tid] = off[tid]; seg_cnt[tid] = tot[tid]; }
    // phase 3: scatter — per-expert pass, ids re-read from LDS (cheap dynamic idx)
    const int base = tid * 32;
#pragma unroll
    for (int e = 0; e < NE; ++e) {
      int p = off[e] + wbase[e * 4 + wv] + pre[e];
#pragma unroll
      for (int k = 0; k < 8; ++k) {
        uint32_t w = lds_ei[tid * 8 + k];
#pragma unroll
        for (int b = 0; b < 4; ++b) {
          int ev = (int)((w >> (8 * b)) & 0xffu);
          if (ev == e) {
            int i = base + k * 4 + b;
            pair_token[p] = i >> 1;
            pair_pos[i] = p;
            p++;
          }
        }
      }
    }
  } else if (bid <= 2048) {
    int i = (bid - 1) * 256 + tid;  // float4 group
    float4 v = ((const float4*)hidden)[i];
    ushort4 o;
    o.x = f2b(v.x); o.y = f2b(v.y); o.z = f2b(v.z); o.w = f2b(v.w);
    ((ushort4*)hidden_b)[i] = o;
  } else {
    // wi transpose: [8][512][2048] f32 -> wi_t [8][2048][512] bf16
    const int R = DM, C = DF;
    int f = bid - 2049;
    int e = f >> 8;
    int cb = (f & 31) * 64, rb = ((f >> 5) & 7) * 64;
    const float* s = wi + (size_t)e * R * C;
    u16* d = wi_t + (size_t)e * R * C;
    int r = tid >> 4, cq = tid & 15;
#pragma unroll
    for (int i = 0; i < 4; ++i) {
      float4 v = *(const float4*)&s[(size_t)(rb + r + 16 * i) * C + cb + cq * 4];
      t[r + 16 * i][cq * 4 + 0] = v.x;
      t[r + 16 * i][cq * 4 + 1] = v.y;
      t[r + 16 * i][cq * 4 + 2] = v.z;
      t[r + 16 * i][cq * 4 + 3] = v.w;
    }
    __syncthreads();
    int rq = tid & 15, c0 = tid >> 4;
#pragma unroll
    for (int i = 0; i < 4; ++i) {
      int c = c0 + 16 * i;
      ushort4 o;
      o.x = f2b(t[rq * 4 + 0][c]);
      o.y = f2b(t[rq * 4 + 1][c]);
      o.z = f2b(t[rq * 4 + 2][c]);
      o.w = f2b(t[rq * 4 + 3][c]);
      *(ushort4*)&d[(size_t)(cb + c) * R + rb + rq * 4] = o;
    }
  }
}

// ---------------- GEMM1: XCD-swizzled BK=64 2-phase + fused wo-transpose z-planes ----
__global__ __launch_bounds__(256) void gemm1_kernel(
    const u16* __restrict__ A,         // hidden_b [4096][512]
    const u16* __restrict__ Bt,        // wi_t [NE][2048][512]
    const int* __restrict__ pair_token,
    const int* __restrict__ seg_off, const int* __restrict__ seg_cnt,
    const int* __restrict__ tl_e, const int* __restrict__ tl_mt,
    u16* __restrict__ out_b,           // act
    const float* __restrict__ tr_src, u16* __restrict__ tr_dst) {
  __shared__ __align__(16) char smem[65536];  // 2 bufs x (A 16K + B 16K)
  if (blockIdx.z > 0) {
    // wo transpose: [8][2048][512] f32 -> wo_t [8][512][2048] bf16
    // Runs in gemm1's LDS/latency slack (GEMM blocks cap at 2/CU by LDS).
    int flat = (blockIdx.z - 1) * 1152 + blockIdx.y * 16 + blockIdx.x;
    if (flat < 2048) {
      const int R = DF, C = DM;
      float(*t)[65] = (float(*)[65])smem;
      int tid = threadIdx.x;
      int e = flat >> 8;
      int cb = (flat & 7) * 64, rb = ((flat >> 3) & 31) * 64;
      const float* s = tr_src + (size_t)e * R * C;
      u16* d = tr_dst + (size_t)e * R * C;
      int r = tid >> 4, cq = tid & 15;
#pragma unroll
      for (int i = 0; i < 4; ++i) {
        float4 v = *(const float4*)&s[(size_t)(rb + r + 16 * i) * C + cb + cq * 4];
        t[r + 16 * i][cq * 4 + 0] = v.x;
        t[r + 16 * i][cq * 4 + 1] = v.y;
        t[r + 16 * i][cq * 4 + 2] = v.z;
        t[r + 16 * i][cq * 4 + 3] = v.w;
      }
      __syncthreads();
      int rq = tid & 15, c0 = tid >> 4;
#pragma unroll
      for (int i = 0; i < 4; ++i) {
        int c = c0 + 16 * i;
        ushort4 o;
        o.x = f2b(t[rq * 4 + 0][c]);
        o.y = f2b(t[rq * 4 + 1][c]);
        o.z = f2b(t[rq * 4 + 2][c]);
        o.w = f2b(t[rq * 4 + 3][c]);
        *(ushort4*)&d[(size_t)(cb + c) * R + rb + rq * 4] = o;
      }
    }
    return;
  }
  const int wg = xcd_swz(blockIdx.y * 16 + blockIdx.x, 1152);
  const int nt = wg & 15;
  const int ytile = wg >> 4;
  const int e = tl_e[ytile];
  if (e < 0) return;
  const int mt = tl_mt[ytile];
  const int cnt = seg_cnt[e];
  const int off = seg_off[e];
  const int tid = threadIdx.x;
  const int wave = tid >> 6, lane = tid & 63;

  const int r0 = wave * 32;
  const int cidx = lane & 7;
  const int rsub = lane >> 3;
  const int csrc = (cidx ^ rsub) * 8;

  const u16* aSrc[4];
  const u16* bSrc[4];
  const u16* BtBase = Bt + ((size_t)e * DF + (size_t)nt * 128) * DM;
#pragma unroll
  for (int g = 0; g < 4; ++g) {
    int rl = r0 + 8 * g + rsub;
    int m = mt * 128 + rl;
    if (m > cnt - 1) m = cnt - 1;
    int srow = pair_token[off + m];
    aSrc[g] = A + (size_t)srow * DM + csrc;
    bSrc[g] = BtBase + (size_t)rl * DM + csrc;
  }

  const int wm = wave >> 1, wn = wave & 1;
  const int rl16 = lane & 15;
  const int q = lane >> 4;
  const int rx = rl16 & 7;

  f32x4 acc[4][4];
#pragma unroll
  for (int i = 0; i < 4; ++i)
#pragma unroll
    for (int j = 0; j < 4; ++j)
#pragma unroll
      for (int r = 0; r < 4; ++r) acc[i][j][r] = 0.0f;

#define G1_STAGE(buf, kofs)                                      \
  do {                                                           \
    u16* Ad_ = (u16*)smem + (buf)*16384;                         \
    u16* Bd_ = Ad_ + 8192;                                       \
    _Pragma("unroll") for (int g = 0; g < 4; ++g) {              \
      gl_lds16(aSrc[g] + (kofs), Ad_ + (r0 + 8 * g) * 64);       \
      gl_lds16(bSrc[g] + (kofs), Bd_ + (r0 + 8 * g) * 64);       \
    }                                                            \
  } while (0)

#define G1_COMPUTE(buf)                                                           \
  do {                                                                            \
    const u16* Al_ = (const u16*)smem + (buf)*16384;                              \
    const u16* Bl_ = Al_ + 8192;                                                  \
    _Pragma("unroll") for (int hb = 0; hb < 2; ++hb) {                            \
      const int jofs = ((q + 4 * hb) ^ rx) * 8;                                   \
      short8 af[4], bf[4];                                                        \
      _Pragma("unroll") for (int mi = 0; mi < 4; ++mi)                            \
        af[mi] = *(const short8*)&Al_[(wm * 64 + mi * 16 + rl16) * 64 + jofs];    \
      _Pragma("unroll") for (int ni = 0; ni < 4; ++ni)                            \
        bf[ni] = *(const short8*)&Bl_[(wn * 64 + ni * 16 + rl16) * 64 + jofs];    \
      _Pragma("unroll") for (int mi = 0; mi < 4; ++mi)                            \
        _Pragma("unroll") for (int ni = 0; ni < 4; ++ni)                          \
          acc[mi][ni] =                                                           \
              __builtin_amdgcn_mfma_f32_16x16x32_bf16(af[mi], bf[ni], acc[mi][ni], 0, 0, 0); \
    }                                                                             \
  } while (0)

  // 2-phase prefetch: STAGE(t+1) in flight during COMPUTE(t); 1 barrier/step.
  G1_STAGE(0, 0);
  __syncthreads();
  int cur = 0;
#pragma unroll
  for (int t = 0; t < (DM / 64) - 1; ++t) {
    G1_STAGE(cur ^ 1, (t + 1) * 64);
    G1_COMPUTE(cur);
    __syncthreads();
    cur ^= 1;
  }
  G1_COMPUTE(cur);
#undef G1_STAGE
#undef G1_COMPUTE

  const int rowq = (lane >> 4) * 4;
#pragma unroll
  for (int mi = 0; mi < 4; ++mi) {
#pragma unroll
    for (int r = 0; r < 4; ++r) {
      int m = mt * 128 + wm * 64 + mi * 16 + rowq + r;
      if (m < cnt) {
        size_t rowp = (size_t)(off + m) * DF;
#pragma unroll
        for (int ni = 0; ni < 4; ++ni) {
          int n = nt * 128 + wn * 64 + ni * 16 + rl16;
          float v = acc[mi][ni][r];
          v = v > 0.0f ? v : 0.0f;
          out_b[rowp + n] = f2b(v);
        }
      }
    }
  }
}

// ---------------- GEMM2: R11-verbatim (BK=64 2-phase + XCD swizzle), f32 partials ----
// Ypart[sp][p][n] = sum_{k in [sp*ks,+ks)} act[p][k] * wo_t[e][n][k]
__global__ __launch_bounds__(256) void gemm2_kernel(
    const u16* __restrict__ A,         // act [8192][2048]
    const u16* __restrict__ Bt,        // wo_t [NE][512][2048]
    const int* __restrict__ seg_off, const int* __restrict__ seg_cnt,
    const int* __restrict__ tl_e, const int* __restrict__ tl_mt,
    float* __restrict__ out_f,
    int nt_mask, int sp_shift, int ks) {
  const int nx = gridDim.x;
  const int wg = xcd_swz(blockIdx.y * nx + blockIdx.x, nx * 72);
  const int xb = wg % nx;
  const int ytile = wg / nx;
  const int e = tl_e[ytile];
  if (e < 0) return;
  const int mt = tl_mt[ytile];
  const int cnt = seg_cnt[e];
  const int off = seg_off[e];
  const int nt = xb & nt_mask;
  const int sp = xb >> sp_shift;
  const int kb = sp * ks;
  const int nsteps = ks >> 6;  // BK=64
  const int tid = threadIdx.x;
  const int wave = tid >> 6, lane = tid & 63;

  __shared__ __align__(16) char smem[65536];  // 2 bufs x (A 16K + B 16K)

  const int r0 = wave * 32;
  const int cidx = lane & 7;
  const int rsub = lane >> 3;
  const int csrc = (cidx ^ rsub) * 8;

  const u16* aSrc[4];
  const u16* bSrc[4];
  const u16* BtBase = Bt + ((size_t)e * DM + (size_t)nt * 128) * DF;
#pragma unroll
  for (int g = 0; g < 4; ++g) {
    int rl = r0 + 8 * g + rsub;
    int m = mt * 128 + rl;
    if (m > cnt - 1) m = cnt - 1;  // clamp padding rows to valid data
    aSrc[g] = A + (size_t)(off + m) * DF + csrc + kb;
    bSrc[g] = BtBase + (size_t)rl * DF + csrc + kb;
  }

  const int wm = wave >> 1, wn = wave & 1;
  const int rl16 = lane & 15;
  const int q = lane >> 4;
  const int rx = rl16 & 7;

  f32x4 acc[4][4];
#pragma unroll
  for (int i = 0; i < 4; ++i)
#pragma unroll
    for (int j = 0; j < 4; ++j)
#pragma unroll
      for (int r = 0; r < 4; ++r) acc[i][j][r] = 0.0f;

#define G2_STAGE(buf, kofs)                                      \
  do {                                                           \
    u16* Ad_ = (u16*)smem + (buf)*16384;                         \
    u16* Bd_ = Ad_ + 8192;                                       \
    _Pragma("unroll") for (int g = 0; g < 4; ++g) {              \
      gl_lds16(aSrc[g] + (kofs), Ad_ + (r0 + 8 * g) * 64);       \
      gl_lds16(bSrc[g] + (kofs), Bd_ + (r0 + 8 * g) * 64);       \
    }                                                            \
  } while (0)

#define G2_COMPUTE(buf)                                                           \
  do {                                                                            \
    const u16* Al_ = (const u16*)smem + (buf)*16384;                              \
    const u16* Bl_ = Al_ + 8192;                                                  \
    _Pragma("unroll") for (int hb = 0; hb < 2; ++hb) {                            \
      const int jofs = ((q + 4 * hb) ^ rx) * 8;                                   \
      short8 af[4], bf[4];                                                        \
      _Pragma("unroll") for (int mi = 0; mi < 4; ++mi)                            \
        af[mi] = *(const short8*)&Al_[(wm * 64 + mi * 16 + rl16) * 64 + jofs];    \
      _Pragma("unroll") for (int ni = 0; ni < 4; ++ni)                            \
        bf[ni] = *(const short8*)&Bl_[(wn * 64 + ni * 16 + rl16) * 64 + jofs];    \
      _Pragma("unroll") for (int mi = 0; mi < 4; ++mi)                            \
        _Pragma("unroll") for (int ni = 0; ni < 4; ++ni)                          \
          acc[mi][ni] =                                                           \
              __builtin_amdgcn_mfma_f32_16x16x32_bf16(af[mi], bf[ni], acc[mi][ni], 0, 0, 0); \
    }                                                                             \
  } while (0)

  // 2-phase prefetch: STAGE(t+1) in flight during COMPUTE(t); 1 barrier/step.
  G2_STAGE(0, 0);
  __syncthreads();
  int cur = 0;
  for (int t = 0; t < nsteps - 1; ++t) {
    G2_STAGE(cur ^ 1, (t + 1) << 6);
    G2_COMPUTE(cur);
    __syncthreads();
    cur ^= 1;
  }
  G2_COMPUTE(cur);
#undef G2_STAGE
#undef G2_COMPUTE

  float* outp = out_f + (size_t)sp * NPAIR * DM;
  const int rowq = (lane >> 4) * 4;
#pragma unroll
  for (int mi = 0; mi < 4; ++mi) {
#pragma unroll
    for (int r = 0; r < 4; ++r) {
      int m = mt * 128 + wm * 64 + mi * 16 + rowq + r;
      if (m < cnt) {
        size_t rowp = (size_t)(off + m) * DM;
#pragma unroll
        for (int ni = 0; ni < 4; ++ni) {
          int n = nt * 128 + wn * 64 + ni * 16 + rl16;
          outp[rowp + n] = acc[mi][ni][r];
        }
      }
    }
  }
}

// ---------------- combine (R9-verbatim, f32 partials) ----------------
__global__ void combine_kernel(const float* __restrict__ hidden,
                               const float* __restrict__ prob,
                               const int* __restrict__ pair_pos,
                               const float* __restrict__ Ypart,
                               float* __restrict__ out, int nsplit) {
  int i = blockIdx.x * 256 + threadIdx.x;  // group of 4 floats
  int t = i >> 7;                          // 128 groups per token (512/4)
  int g = i & 127;
  int p0 = pair_pos[2 * t], p1 = pair_pos[2 * t + 1];
  float c0 = 0.5f * prob[2 * t];
  float c1 = 0.25f * prob[2 * t + 1];
  float4 a = {0.f, 0.f, 0.f, 0.f}, b = {0.f, 0.f, 0.f, 0.f};
  for (int s = 0; s < nsplit; ++s) {
    const float4* Y = (const float4*)(Ypart + (size_t)s * NPAIR * DM);
    float4 va = Y[(size_t)p0 * 128 + g];
    float4 vb = Y[(size_t)p1 * 128 + g];
    a.x += va.x; a.y += va.y; a.z += va.z; a.w += va.w;
    b.x += vb.x; b.y += vb.y; b.z += vb.z; b.w += vb.w;
  }
  float4 h = ((const float4*)hidden)[i];
  float4 r, o;
  r.x = c0 * a.x + c1 * b.x;
  r.y = c0 * a.y + c1 * b.y;
  r.z = c0 * a.z + c1 * b.z;
  r.w = c0 * a.w + c1 * b.w;
  o.x = (r.x != 0.0f) ? r.x : h.x;
  o.y = (r.y != 0.0f) ? r.y : h.y;
  o.z = (r.z != 0.0f) ? r.z : h.z;
  o.w = (r.w != 0.0f) ? r.w : h.w;
  ((float4*)out)[i] = o;
}

extern "C" void kernel_launch(void* const* d_in, const int* in_sizes, int n_in,
                              void* d_out, int out_size, void* d_ws, size_t ws_size,
                              hipStream_t stream) {
  const float* hidden = (const float*)d_in[0];
  const float* prob = (const float*)d_in[1];
  const float* wi = (const float*)d_in[2];
  const float* wo = (const float*)d_in[3];
  const int* eidx = (const int*)d_in[4];
  float* out = (float*)d_out;

  char* ws = (char*)d_ws;
  u16* hidden_b = (u16*)(ws + 0);                     //  4 MB [4096][512] bf16
  u16* wi_t = (u16*)(ws + ((size_t)4 << 20));         // 16 MB [8][2048][512] bf16 (wi^T)
  u16* wo_t = (u16*)(ws + ((size_t)20 << 20));        // 16 MB [8][512][2048] bf16 (wo^T)
  u16* act = (u16*)(ws + ((size_t)36 << 20));         // 32 MB [8192][2048] bf16
  float* Ypart = (float*)(ws + ((size_t)68 << 20));   // 32 MB [2][8192][512] f32
  char* smalls = ws + ((size_t)132 << 20);
  int* pair_token = (int*)(smalls);
  int* pair_pos = (int*)(smalls + (64u << 10));
  int* seg_off = (int*)(smalls + (128u << 10));
  int* seg_cnt = (int*)(smalls + (128u << 10) + 256);
  int* tl_e = (int*)(smalls + (129u << 10));          // 128 ints
  int* tl_mt = (int*)(smalls + (129u << 10) + 512);   // 128 ints

  // 1) prep: routing+tilelist | hidden cvt | tr wi
  hipLaunchKernelGGL(prep_kernel, dim3(4097), dim3(256), 0, stream,
                     eidx, hidden, hidden_b, wi, wi_t,
                     pair_token, pair_pos, seg_off, seg_cnt, tl_e, tl_mt);
  // 2) GEMM1 (z=0, XCD-swizzled): act = relu(hidden @ wi[e]); + fused wo tr (z=1,2)
  hipLaunchKernelGGL(gemm1_kernel, dim3(16, 72, 3), dim3(256), 0, stream,
                     hidden_b, wi_t, pair_token, seg_off, seg_cnt, tl_e, tl_mt,
                     act, wo, wo_t);
  // 3) GEMM2: Ypart[sp] = act @ wo[e] (f32 partials); K=2048 split 2; BK=64 dbuf
  hipLaunchKernelGGL(gemm2_kernel, dim3(4 * SPLIT, 72, 1), dim3(256), 0, stream,
                     act, wo_t, seg_off, seg_cnt, tl_e, tl_mt,
                     Ypart, 3, 2, DF / SPLIT);
  // 4) combine + where(next!=0, next, hidden)
  hipLaunchKernelGGL(combine_kernel, dim3(2048), dim3(256), 0, stream,
                     hidden, prob, pair_pos, Ypart, out, SPLIT);
}

// Round 14
// 188.489 us; speedup vs baseline: 1.0671x; 1.0165x over previous
//
#include <hip/hip_runtime.h>
#include <cstdint>
#include <cstddef>

#define TOKENS 4096
#define DM 512
#define DF 2048
#define NE 8
#define NPAIR 8192  // TOKENS * TOPK
#define SPLIT 2     // split-K factor for GEMM2 (f32 partials)

typedef unsigned short u16;
typedef __attribute__((ext_vector_type(8))) short short8;
typedef __attribute__((ext_vector_type(4))) float f32x4;

// fp32 -> bf16 round-to-nearest-even (finite inputs only)
__device__ __forceinline__ u16 f2b(float x) {
  uint32_t u = __builtin_bit_cast(uint32_t, x);
  uint32_t r = (u + 0x7fffu + ((u >> 16) & 1u)) >> 16;
  return (u16)r;
}

__device__ __forceinline__ void gl_lds16(const void* gsrc, void* ldst) {
  __builtin_amdgcn_global_load_lds(
      (__attribute__((address_space(1))) void*)(gsrc),
      (__attribute__((address_space(3))) void*)(ldst), 16, 0, 0);
}

// bijective XCD swizzle (requires nwg % 8 == 0): blocks sharing an M-tile
// get consecutive wg on one XCD -> shared A-chunk/B-panels become L2-local.
__device__ __forceinline__ int xcd_swz(int flat, int nwg) {
  return (flat & 7) * (nwg >> 3) + (flat >> 3);
}

// ---------------- prep: routing (atomic-free, R9-verbatim) | hidden cvt | tr wi | tr wo ----
__global__ __launch_bounds__(256) void prep_kernel(
    const int* __restrict__ eidx, const float* __restrict__ hidden, u16* __restrict__ hidden_b,
    const float* __restrict__ wi, u16* __restrict__ wi_t,
    const float* __restrict__ wo, u16* __restrict__ wo_t,
    int* __restrict__ pair_token, int* __restrict__ pair_pos,
    int* __restrict__ seg_off, int* __restrict__ seg_cnt,
    int* __restrict__ tl_e, int* __restrict__ tl_mt) {
  __shared__ __align__(16) float t[64][65];
  int bid = blockIdx.x;
  int tid = threadIdx.x;
  if (bid == 0) {
    // ---- atomic-free routing: histogram + scan + scatter ----
    int* wsums = (int*)&t[0][0];   // 32 ints
    int* wbase = wsums + 32;       // 32 ints
    int* tot = wbase + 32;         // 8 ints
    int* off = tot + 8;            // 8 ints
    const int lane = tid & 63, wv = tid >> 6;
    int ei[32];
#pragma unroll
    for (int k = 0; k < 8; ++k) {
      int4 v = ((const int4*)eidx)[tid * 8 + k];
      ei[4 * k + 0] = v.x; ei[4 * k + 1] = v.y;
      ei[4 * k + 2] = v.z; ei[4 * k + 3] = v.w;
    }
    int c[8];
#pragma unroll
    for (int e = 0; e < NE; ++e) c[e] = 0;
#pragma unroll
    for (int j = 0; j < 32; ++j)
#pragma unroll
      for (int e = 0; e < NE; ++e) c[e] += (ei[j] == e) ? 1 : 0;
    int pre[8], wtot[8];
#pragma unroll
    for (int e = 0; e < NE; ++e) {
      int v = c[e];
      int s = v;
#pragma unroll
      for (int d = 1; d < 64; d <<= 1) {
        int u = __shfl_up(s, d, 64);
        if (lane >= d) s += u;
      }
      pre[e] = s - v;
      wtot[e] = __shfl(s, 63, 64);
    }
    if (lane == 0) {
#pragma unroll
      for (int e = 0; e < NE; ++e) wsums[e * 4 + wv] = wtot[e];
    }
    __syncthreads();
    if (tid < 32) {
      int e = tid >> 2, w = tid & 3;
      int b = 0;
      for (int j = 0; j < 4; ++j) {
        int v = wsums[e * 4 + j];
        if (j < w) b += v;
      }
      wbase[e * 4 + w] = b;
      if (w == 3) tot[e] = b + wsums[e * 4 + 3];
    }
    __syncthreads();
    if (tid == 0) {
      int a = 0;
      for (int e = 0; e < NE; ++e) { off[e] = a; a += tot[e]; }
      int n = 0;
      for (int e = 0; e < NE; ++e) {
        int ntl = (tot[e] + 127) >> 7;
        for (int m = 0; m < ntl && n < 128; ++m, ++n) { tl_e[n] = e; tl_mt[n] = m; }
      }
      for (; n < 128; ++n) { tl_e[n] = -1; tl_mt[n] = 0; }
    }
    __syncthreads();
    if (tid < NE) { seg_off[tid] = off[tid]; seg_cnt[tid] = tot[tid]; }
    const int base = tid * 32;
#pragma unroll
    for (int e = 0; e < NE; ++e) {
      int p = off[e] + wbase[e * 4 + wv] + pre[e];
#pragma unroll
      for (int j = 0; j < 32; ++j) {
        if (ei[j] == e) {
          int i = base + j;
          pair_token[p] = i >> 1;
          pair_pos[i] = p;
          p++;
        }
      }
    }
  } else if (bid <= 2048) {
    int i = (bid - 1) * 256 + tid;  // float4 group
    float4 v = ((const float4*)hidden)[i];
    ushort4 o;
    o.x = f2b(v.x); o.y = f2b(v.y); o.z = f2b(v.z); o.w = f2b(v.w);
    ((ushort4*)hidden_b)[i] = o;
  } else if (bid <= 4096) {
    // wi transpose: [8][512][2048] f32 -> wi_t [8][2048][512] bf16
    const int R = DM, C = DF;
    int f = bid - 2049;
    int e = f >> 8;
    int cb = (f & 31) * 64, rb = ((f >> 5) & 7) * 64;
    const float* s = wi + (size_t)e * R * C;
    u16* d = wi_t + (size_t)e * R * C;
    int r = tid >> 4, cq = tid & 15;
#pragma unroll
    for (int i = 0; i < 4; ++i) {
      float4 v = *(const float4*)&s[(size_t)(rb + r + 16 * i) * C + cb + cq * 4];
      t[r + 16 * i][cq * 4 + 0] = v.x;
      t[r + 16 * i][cq * 4 + 1] = v.y;
      t[r + 16 * i][cq * 4 + 2] = v.z;
      t[r + 16 * i][cq * 4 + 3] = v.w;
    }
    __syncthreads();
    int rq = tid & 15, c0 = tid >> 4;
#pragma unroll
    for (int i = 0; i < 4; ++i) {
      int c = c0 + 16 * i;
      ushort4 o;
      o.x = f2b(t[rq * 4 + 0][c]);
      o.y = f2b(t[rq * 4 + 1][c]);
      o.z = f2b(t[rq * 4 + 2][c]);
      o.w = f2b(t[rq * 4 + 3][c]);
      *(ushort4*)&d[(size_t)(cb + c) * R + rb + rq * 4] = o;
    }
  } else {
    // wo transpose: [8][2048][512] f32 -> wo_t [8][512][2048] bf16
    const int R = DF, C = DM;
    int f = bid - 4097;
    int e = f >> 8;
    int cb = (f & 7) * 64, rb = ((f >> 3) & 31) * 64;
    const float* s = wo + (size_t)e * R * C;
    u16* d = wo_t + (size_t)e * R * C;
    int r = tid >> 4, cq = tid & 15;
#pragma unroll
    for (int i = 0; i < 4; ++i) {
      float4 v = *(const float4*)&s[(size_t)(rb + r + 16 * i) * C + cb + cq * 4];
      t[r + 16 * i][cq * 4 + 0] = v.x;
      t[r + 16 * i][cq * 4 + 1] = v.y;
      t[r + 16 * i][cq * 4 + 2] = v.z;
      t[r + 16 * i][cq * 4 + 3] = v.w;
    }
    __syncthreads();
    int rq = tid & 15, c0 = tid >> 4;
#pragma unroll
    for (int i = 0; i < 4; ++i) {
      int c = c0 + 16 * i;
      ushort4 o;
      o.x = f2b(t[rq * 4 + 0][c]);
      o.y = f2b(t[rq * 4 + 1][c]);
      o.z = f2b(t[rq * 4 + 2][c]);
      o.w = f2b(t[rq * 4 + 3][c]);
      *(ushort4*)&d[(size_t)(cb + c) * R + rb + rq * 4] = o;
    }
  }
}

// ---------------- GEMM1: R9 body + XCD swizzle (index remap only) ----
__global__ __launch_bounds__(256) void gemm1_kernel(
    const u16* __restrict__ A,         // hidden_b [4096][512]
    const u16* __restrict__ Bt,        // wi_t [NE][2048][512]
    const int* __restrict__ pair_token,
    const int* __restrict__ seg_off, const int* __restrict__ seg_cnt,
    const int* __restrict__ tl_e, const int* __restrict__ tl_mt,
    u16* __restrict__ out_b) {         // act
  __shared__ __align__(16) char smem[65536];  // 2 bufs x (A 16K + B 16K)
  const int wg = xcd_swz(blockIdx.y * 16 + blockIdx.x, 1152);
  const int nt = wg & 15;
  const int ytile = wg >> 4;
  const int e = tl_e[ytile];
  if (e < 0) return;
  const int mt = tl_mt[ytile];
  const int cnt = seg_cnt[e];
  const int off = seg_off[e];
  const int tid = threadIdx.x;
  const int wave = tid >> 6, lane = tid & 63;

  const int r0 = wave * 32;
  const int cidx = lane & 7;
  const int rsub = lane >> 3;
  const int csrc = (cidx ^ rsub) * 8;

  const u16* aSrc[4];
  const u16* bSrc[4];
  const u16* BtBase = Bt + ((size_t)e * DF + (size_t)nt * 128) * DM;
#pragma unroll
  for (int g = 0; g < 4; ++g) {
    int rl = r0 + 8 * g + rsub;
    int m = mt * 128 + rl;
    if (m > cnt - 1) m = cnt - 1;
    int srow = pair_token[off + m];
    aSrc[g] = A + (size_t)srow * DM + csrc;
    bSrc[g] = BtBase + (size_t)rl * DM + csrc;
  }

  const int wm = wave >> 1, wn = wave & 1;
  const int rl16 = lane & 15;
  const int q = lane >> 4;
  const int rx = rl16 & 7;

  f32x4 acc[4][4];
#pragma unroll
  for (int i = 0; i < 4; ++i)
#pragma unroll
    for (int j = 0; j < 4; ++j)
#pragma unroll
      for (int r = 0; r < 4; ++r) acc[i][j][r] = 0.0f;

#define G1_STAGE(buf, kofs)                                      \
  do {                                                           \
    u16* Ad_ = (u16*)smem + (buf)*16384;                         \
    u16* Bd_ = Ad_ + 8192;                                       \
    _Pragma("unroll") for (int g = 0; g < 4; ++g) {              \
      gl_lds16(aSrc[g] + (kofs), Ad_ + (r0 + 8 * g) * 64);       \
      gl_lds16(bSrc[g] + (kofs), Bd_ + (r0 + 8 * g) * 64);       \
    }                                                            \
  } while (0)

#define G1_COMPUTE(buf)                                                           \
  do {                                                                            \
    const u16* Al_ = (const u16*)smem + (buf)*16384;                              \
    const u16* Bl_ = Al_ + 8192;                                                  \
    _Pragma("unroll") for (int hb = 0; hb < 2; ++hb) {                            \
      const int jofs = ((q + 4 * hb) ^ rx) * 8;                                   \
      short8 af[4], bf[4];                                                        \
      _Pragma("unroll") for (int mi = 0; mi < 4; ++mi)                            \
        af[mi] = *(const short8*)&Al_[(wm * 64 + mi * 16 + rl16) * 64 + jofs];    \
      _Pragma("unroll") for (int ni = 0; ni < 4; ++ni)                            \
        bf[ni] = *(const short8*)&Bl_[(wn * 64 + ni * 16 + rl16) * 64 + jofs];    \
      _Pragma("unroll") for (int mi = 0; mi < 4; ++mi)                            \
        _Pragma("unroll") for (int ni = 0; ni < 4; ++ni)                          \
          acc[mi][ni] =                                                           \
              __builtin_amdgcn_mfma_f32_16x16x32_bf16(af[mi], bf[ni], acc[mi][ni], 0, 0, 0); \
    }                                                                             \
  } while (0)

  // 2-phase prefetch: STAGE(t+1) in flight during COMPUTE(t); 1 barrier/step.
  G1_STAGE(0, 0);
  __syncthreads();
  int cur = 0;
#pragma unroll
  for (int t = 0; t < (DM / 64) - 1; ++t) {
    G1_STAGE(cur ^ 1, (t + 1) * 64);
    G1_COMPUTE(cur);
    __syncthreads();
    cur ^= 1;
  }
  G1_COMPUTE(cur);
#undef G1_STAGE
#undef G1_COMPUTE

  const int rowq = (lane >> 4) * 4;
#pragma unroll
  for (int mi = 0; mi < 4; ++mi) {
#pragma unroll
    for (int r = 0; r < 4; ++r) {
      int m = mt * 128 + wm * 64 + mi * 16 + rowq + r;
      if (m < cnt) {
        size_t rowp = (size_t)(off + m) * DF;
#pragma unroll
        for (int ni = 0; ni < 4; ++ni) {
          int n = nt * 128 + wn * 64 + ni * 16 + rl16;
          float v = acc[mi][ni][r];
          v = v > 0.0f ? v : 0.0f;
          out_b[rowp + n] = f2b(v);
        }
      }
    }
  }
}

// ---------------- GEMM2: R9 body + XCD swizzle (index remap only) ----
// Ypart[sp][p][n] = sum_{k in [sp*ks,+ks)} act[p][k] * wo_t[e][n][k]
__global__ __launch_bounds__(256) void gemm2_kernel(
    const u16* __restrict__ A,         // act [8192][2048]
    const u16* __restrict__ Bt,        // wo_t [NE][512][2048]
    const int* __restrict__ seg_off, const int* __restrict__ seg_cnt,
    const int* __restrict__ tl_e, const int* __restrict__ tl_mt,
    float* __restrict__ out_f,
    int nt_mask, int sp_shift, int ks) {
  const int nx = gridDim.x;
  const int wg = xcd_swz(blockIdx.y * nx + blockIdx.x, nx * 72);
  const int xb = wg % nx;
  const int ytile = wg / nx;
  const int e = tl_e[ytile];
  if (e < 0) return;
  const int mt = tl_mt[ytile];
  const int cnt = seg_cnt[e];
  const int off = seg_off[e];
  const int nt = xb & nt_mask;
  const int sp = xb >> sp_shift;
  const int kb = sp * ks;
  const int nsteps = ks >> 6;  // BK=64
  const int tid = threadIdx.x;
  const int wave = tid >> 6, lane = tid & 63;

  __shared__ __align__(16) char smem[65536];  // 2 bufs x (A 16K + B 16K)

  const int r0 = wave * 32;
  const int cidx = lane & 7;
  const int rsub = lane >> 3;
  const int csrc = (cidx ^ rsub) * 8;

  const u16* aSrc[4];
  const u16* bSrc[4];
  const u16* BtBase = Bt + ((size_t)e * DM + (size_t)nt * 128) * DF;
#pragma unroll
  for (int g = 0; g < 4; ++g) {
    int rl = r0 + 8 * g + rsub;
    int m = mt * 128 + rl;
    if (m > cnt - 1) m = cnt - 1;  // clamp padding rows to valid data
    aSrc[g] = A + (size_t)(off + m) * DF + csrc + kb;
    bSrc[g] = BtBase + (size_t)rl * DF + csrc + kb;
  }

  const int wm = wave >> 1, wn = wave & 1;
  const int rl16 = lane & 15;
  const int q = lane >> 4;
  const int rx = rl16 & 7;

  f32x4 acc[4][4];
#pragma unroll
  for (int i = 0; i < 4; ++i)
#pragma unroll
    for (int j = 0; j < 4; ++j)
#pragma unroll
      for (int r = 0; r < 4; ++r) acc[i][j][r] = 0.0f;

#define G2_STAGE(buf, kofs)                                      \
  do {                                                           \
    u16* Ad_ = (u16*)smem + (buf)*16384;                         \
    u16* Bd_ = Ad_ + 8192;                                       \
    _Pragma("unroll") for (int g = 0; g < 4; ++g) {              \
      gl_lds16(aSrc[g] + (kofs), Ad_ + (r0 + 8 * g) * 64);       \
      gl_lds16(bSrc[g] + (kofs), Bd_ + (r0 + 8 * g) * 64);       \
    }                                                            \
  } while (0)

#define G2_COMPUTE(buf)                                                           \
  do {                                                                            \
    const u16* Al_ = (const u16*)smem + (buf)*16384;                              \
    const u16* Bl_ = Al_ + 8192;                                                  \
    _Pragma("unroll") for (int hb = 0; hb < 2; ++hb) {                            \
      const int jofs = ((q + 4 * hb) ^ rx) * 8;                                   \
      short8 af[4], bf[4];                                                        \
      _Pragma("unroll") for (int mi = 0; mi < 4; ++mi)                            \
        af[mi] = *(const short8*)&Al_[(wm * 64 + mi * 16 + rl16) * 64 + jofs];    \
      _Pragma("unroll") for (int ni = 0; ni < 4; ++ni)                            \
        bf[ni] = *(const short8*)&Bl_[(wn * 64 + ni * 16 + rl16) * 64 + jofs];    \
      _Pragma("unroll") for (int mi = 0; mi < 4; ++mi)                            \
        _Pragma("unroll") for (int ni = 0; ni < 4; ++ni)                          \
          acc[mi][ni] =                                                           \
              __builtin_amdgcn_mfma_f32_16x16x32_bf16(af[mi], bf[ni], acc[mi][ni], 0, 0, 0); \
    }                                                                             \
  } while (0)

  // 2-phase prefetch: STAGE(t+1) in flight during COMPUTE(t); 1 barrier/step.
  G2_STAGE(0, 0);
  __syncthreads();
  int cur = 0;
  for (int t = 0; t < nsteps - 1; ++t) {
    G2_STAGE(cur ^ 1, (t + 1) << 6);
    G2_COMPUTE(cur);
    __syncthreads();
    cur ^= 1;
  }
  G2_COMPUTE(cur);
#undef G2_STAGE
#undef G2_COMPUTE

  float* outp = out_f + (size_t)sp * NPAIR * DM;
  const int rowq = (lane >> 4) * 4;
#pragma unroll
  for (int mi = 0; mi < 4; ++mi) {
#pragma unroll
    for (int r = 0; r < 4; ++r) {
      int m = mt * 128 + wm * 64 + mi * 16 + rowq + r;
      if (m < cnt) {
        size_t rowp = (size_t)(off + m) * DM;
#pragma unroll
        for (int ni = 0; ni < 4; ++ni) {
          int n = nt * 128 + wn * 64 + ni * 16 + rl16;
          outp[rowp + n] = acc[mi][ni][r];
        }
      }
    }
  }
}

// ---------------- combine (R9-verbatim, f32 partials) ----------------
__global__ void combine_kernel(const float* __restrict__ hidden,
                               const float* __restrict__ prob,
                               const int* __restrict__ pair_pos,
                               const float* __restrict__ Ypart,
                               float* __restrict__ out, int nsplit) {
  int i = blockIdx.x * 256 + threadIdx.x;  // group of 4 floats
  int t = i >> 7;                          // 128 groups per token (512/4)
  int g = i & 127;
  int p0 = pair_pos[2 * t], p1 = pair_pos[2 * t + 1];
  float c0 = 0.5f * prob[2 * t];
  float c1 = 0.25f * prob[2 * t + 1];
  float4 a = {0.f, 0.f, 0.f, 0.f}, b = {0.f, 0.f, 0.f, 0.f};
  for (int s = 0; s < nsplit; ++s) {
    const float4* Y = (const float4*)(Ypart + (size_t)s * NPAIR * DM);
    float4 va = Y[(size_t)p0 * 128 + g];
    float4 vb = Y[(size_t)p1 * 128 + g];
    a.x += va.x; a.y += va.y; a.z += va.z; a.w += va.w;
    b.x += vb.x; b.y += vb.y; b.z += vb.z; b.w += vb.w;
  }
  float4 h = ((const float4*)hidden)[i];
  float4 r, o;
  r.x = c0 * a.x + c1 * b.x;
  r.y = c0 * a.y + c1 * b.y;
  r.z = c0 * a.z + c1 * b.z;
  r.w = c0 * a.w + c1 * b.w;
  o.x = (r.x != 0.0f) ? r.x : h.x;
  o.y = (r.y != 0.0f) ? r.y : h.y;
  o.z = (r.z != 0.0f) ? r.z : h.z;
  o.w = (r.w != 0.0f) ? r.w : h.w;
  ((float4*)out)[i] = o;
}

extern "C" void kernel_launch(void* const* d_in, const int* in_sizes, int n_in,
                              void* d_out, int out_size, void* d_ws, size_t ws_size,
                              hipStream_t stream) {
  const float* hidden = (const float*)d_in[0];
  const float* prob = (const float*)d_in[1];
  const float* wi = (const float*)d_in[2];
  const float* wo = (const float*)d_in[3];
  const int* eidx = (const int*)d_in[4];
  float* out = (float*)d_out;

  char* ws = (char*)d_ws;
  u16* hidden_b = (u16*)(ws + 0);                     //  4 MB [4096][512] bf16
  u16* wi_t = (u16*)(ws + ((size_t)4 << 20));         // 16 MB [8][2048][512] bf16 (wi^T)
  u16* wo_t = (u16*)(ws + ((size_t)20 << 20));        // 16 MB [8][512][2048] bf16 (wo^T)
  u16* act = (u16*)(ws + ((size_t)36 << 20));         // 32 MB [8192][2048] bf16
  float* Ypart = (float*)(ws + ((size_t)68 << 20));   // 32 MB [2][8192][512] f32
  char* smalls = ws + ((size_t)132 << 20);
  int* pair_token = (int*)(smalls);
  int* pair_pos = (int*)(smalls + (64u << 10));
  int* seg_off = (int*)(smalls + (128u << 10));
  int* seg_cnt = (int*)(smalls + (128u << 10) + 256);
  int* tl_e = (int*)(smalls + (129u << 10));          // 128 ints
  int* tl_mt = (int*)(smalls + (129u << 10) + 512);   // 128 ints

  // 1) prep: routing+tilelist | hidden cvt | tr wi | tr wo
  hipLaunchKernelGGL(prep_kernel, dim3(6145), dim3(256), 0, stream,
                     eidx, hidden, hidden_b, wi, wi_t, wo, wo_t,
                     pair_token, pair_pos, seg_off, seg_cnt, tl_e, tl_mt);
  // 2) GEMM1: act = relu(hidden @ wi[e])  (XCD-swizzled grid)
  hipLaunchKernelGGL(gemm1_kernel, dim3(16, 72, 1), dim3(256), 0, stream,
                     hidden_b, wi_t, pair_token, seg_off, seg_cnt, tl_e, tl_mt,
                     act);
  // 3) GEMM2: Ypart[sp] = act @ wo[e] (f32 partials); K=2048 split 2; BK=64 dbuf
  hipLaunchKernelGGL(gemm2_kernel, dim3(4 * SPLIT, 72, 1), dim3(256), 0, stream,
                     act, wo_t, seg_off, seg_cnt, tl_e, tl_mt,
                     Ypart, 3, 2, DF / SPLIT);
  // 4) combine + where(next!=0, next, hidden)
  hipLaunchKernelGGL(combine_kernel, dim3(2048), dim3(256), 0, stream,
                     hidden, prob, pair_pos, Ypart, out, SPLIT);
}